// Round 3
// baseline (218.969 us; speedup 1.0000x reference)
//
#include <hip/hip_runtime.h>

#define NEGF 1.0e12f

constexpr int Hdim = 768;
constexpr int NC   = 160;   // 128 (W1) + 32 (W2) output columns
constexpr int ROWS = 4096;  // B*S
constexpr int SEQ  = 512;

typedef __attribute__((ext_vector_type(8))) short  short8;   // 8 bf16
typedef __attribute__((ext_vector_type(4))) float  floatx4;

__device__ inline unsigned short f2bf(float f) {
    union { float f; unsigned u; } v; v.f = f;
    return (unsigned short)((v.u + 0x8000u) >> 16);
}

// ---------------------------------------------------------------------------
// Kernel AB: t = x @ [W1|W2] (full K=768, bf16 MFMA, software-pipelined),
// then bias + RoPE + typing-split in-block (t round-trips through LDS only).
// Grid 128 x 256 threads (4 waves). Block: 32 rows x 160 cols.
// Wave w: row-group rg=w>>1 (16 rows), col-group cgp=w&1 (80 cols = 5 tiles).
// ---------------------------------------------------------------------------
__global__ __launch_bounds__(256) void gemm_rope_fused_k(
    const float* __restrict__ x, const float* __restrict__ W1,
    const float* __restrict__ b1, const float* __restrict__ W2,
    const float* __restrict__ b2, unsigned short* __restrict__ startbf,
    unsigned short* __restrict__ endbf, float* __restrict__ tyn,
    float* __restrict__ tym)
{
    __shared__ __align__(16) unsigned short xs[32 * 40];   // [m][k] bf16
    __shared__ __align__(16) unsigned short ws[NC * 40];   // [n][k] bf16
    __shared__ __align__(16) float ts[32 * 160];           // combined t, fp32

    const int tid  = threadIdx.x;
    const int wave = tid >> 6;
    const int lane = tid & 63;
    const int quad = lane >> 4;
    const int nl   = lane & 15;
    const int rg   = wave >> 1;       // 0/1: rows rg*16..+15
    const int cgp  = wave & 1;        // 0/1: col tiles cgp*5..+4
    const int r0   = blockIdx.x * 32;

    // W staging task decomposition: task in [0,640): c=task%160, kq=(task/160)*8
    const int c0  = tid % 160,         kq0 = (tid / 160) * 8;
    const int c1  = (tid + 256) % 160, kq1 = ((tid + 256) / 160) * 8;
    const int c2  = (tid + 512) % 160, kq2 = ((tid + 512) / 160) * 8;  // tid<128 only
    const int xrow = tid >> 3;
    const int xk4  = (tid & 7) * 4;

    floatx4 acc[5];
#pragma unroll
    for (int t = 0; t < 5; t++) acc[t] = (floatx4)(0.0f);

    float4 xv;
    float  wf0[8], wf1[8], wf2[8];

    auto loadW8 = [&](int c, int kq, int kb, float* f) {
        if (c < 128) {
            const float* wp = W1 + (size_t)(kb + kq) * 128 + c;
#pragma unroll
            for (int j = 0; j < 8; j++) f[j] = wp[(size_t)j * 128];
        } else {
            const float* wp = W2 + (size_t)(kb + kq) * 32 + (c - 128);
#pragma unroll
            for (int j = 0; j < 8; j++) f[j] = wp[(size_t)j * 32];
        }
    };

    // prologue: load kt=0
    xv = *(const float4*)(x + (size_t)(r0 + xrow) * Hdim + 0 + xk4);
    loadW8(c0, kq0, 0, wf0);
    loadW8(c1, kq1, 0, wf1);
    if (tid < 128) loadW8(c2, kq2, 0, wf2);

    for (int kt = 0; kt < 24; kt++) {
        // commit current regs to LDS
        {
            short4 sv;
            sv.x = (short)f2bf(xv.x); sv.y = (short)f2bf(xv.y);
            sv.z = (short)f2bf(xv.z); sv.w = (short)f2bf(xv.w);
            *(short4*)(xs + xrow * 40 + xk4) = sv;
            short8 s0, s1, s2;
#pragma unroll
            for (int j = 0; j < 8; j++) { s0[j] = (short)f2bf(wf0[j]); s1[j] = (short)f2bf(wf1[j]); }
            *(short8*)(ws + c0 * 40 + kq0) = s0;
            *(short8*)(ws + c1 * 40 + kq1) = s1;
            if (tid < 128) {
#pragma unroll
                for (int j = 0; j < 8; j++) s2[j] = (short)f2bf(wf2[j]);
                *(short8*)(ws + c2 * 40 + kq2) = s2;
            }
        }
        __syncthreads();

        // prefetch next k-tile into registers (overlaps MFMA below)
        if (kt < 23) {
            const int kb = (kt + 1) * 32;
            xv = *(const float4*)(x + (size_t)(r0 + xrow) * Hdim + kb + xk4);
            loadW8(c0, kq0, kb, wf0);
            loadW8(c1, kq1, kb, wf1);
            if (tid < 128) loadW8(c2, kq2, kb, wf2);
        }

        short8 af = *(const short8*)(xs + (rg * 16 + nl) * 40 + quad * 8);
#pragma unroll
        for (int t = 0; t < 5; t++) {
            short8 bf = *(const short8*)(ws + ((cgp * 5 + t) * 16 + nl) * 40 + quad * 8);
            acc[t] = __builtin_amdgcn_mfma_f32_16x16x32_bf16(af, bf, acc[t], 0, 0, 0);
        }
        __syncthreads();
    }

    // acc -> ts LDS: elem (t,r) at row rg*16+quad*4+r, col (cgp*5+t)*16+nl
#pragma unroll
    for (int t = 0; t < 5; t++) {
#pragma unroll
        for (int r = 0; r < 4; r++) {
            ts[(rg * 16 + quad * 4 + r) * 160 + (cgp * 5 + t) * 16 + nl] = acc[t][r];
        }
    }
    __syncthreads();

    // B-phase: bias + RoPE + typing split. 2048 units, 8 per thread.
    for (int idx = tid; idx < 32 * 64; idx += 256) {
        const int lrow = idx >> 6;
        const int u    = idx & 63;
        const int grow = r0 + lrow;
        const int b    = grow >> 9;
        const int s    = grow & 511;
        if (u < 32) {
            const int i = u;
            float4 tv = *(const float4*)(ts + lrow * 160 + 4 * i);
            float4 bv = *(const float4*)(b1 + 4 * i);
            float t0 = tv.x + bv.x, t1 = tv.y + bv.y;
            float t2 = tv.z + bv.z, t3 = tv.w + bv.w;
            float freq = __powf(10000.0f, -(float)i * (1.0f / 32.0f));
            float ang  = (float)s * freq;
            float sn, cs;
            __sincosf(ang, &sn, &cs);
            float so0 = (t0 * cs - t2 * sn) * 0.125f;   // fold 1/sqrt(64)
            float so1 = (t2 * cs + t0 * sn) * 0.125f;
            float eo0 = t1 * cs - t3 * sn;
            float eo1 = t3 * cs + t1 * sn;
            ushort2 sp; sp.x = f2bf(so0); sp.y = f2bf(so1);
            ushort2 ep; ep.x = f2bf(eo0); ep.y = f2bf(eo1);
            *(ushort2*)(startbf + (size_t)grow * 64 + 2 * i) = sp;
            *(ushort2*)(endbf   + (size_t)grow * 64 + 2 * i) = ep;
        } else {
            const int j = u - 32;
            float t = ts[lrow * 160 + 128 + j] + b2[j];
            float v = t * 0.5f;
            const int l = j >> 1;
            if ((j & 1) == 0) tyn[((size_t)b * 16 + l) * SEQ + s] = v;
            else              tym[((size_t)b * 16 + l) * SEQ + s] = v;
        }
    }
}

// ---------------------------------------------------------------------------
// Kernel C: span = start.end^T via bf16 MFMA + 16-plane epilogue from D regs.
// Grid (8 n-tiles, 8 m-tiles, 8 batches) x 256 threads; 64x64 (m,n) tile.
// ---------------------------------------------------------------------------
__global__ __launch_bounds__(256) void entity_k(
    const unsigned short* __restrict__ startbf, const unsigned short* __restrict__ endbf,
    const float* __restrict__ tyn, const float* __restrict__ tym,
    const int* __restrict__ amask, float* __restrict__ out)
{
    __shared__ __align__(16) unsigned short sA[64 * 72];
    __shared__ __align__(16) unsigned short sB[64 * 72];
    __shared__ float tyn_s[16 * 64];
    __shared__ float tym_s[16 * 64];
    __shared__ float mrow_s[64];
    __shared__ float mcol_s[64];

    const int tid = threadIdx.x;
    const int b   = blockIdx.z;
    const int m0  = blockIdx.y * 64;
    const int n0  = blockIdx.x * 64;

    for (int t = tid; t < 512; t += 256) {
        int row = t >> 3;
        int kq  = (t & 7) * 8;
        *(short8*)(sA + row * 72 + kq) =
            *(const short8*)(startbf + (size_t)(b * SEQ + m0 + row) * 64 + kq);
        *(short8*)(sB + row * 72 + kq) =
            *(const short8*)(endbf + (size_t)(b * SEQ + n0 + row) * 64 + kq);
    }
    for (int t = tid; t < 16 * 64; t += 256) {
        int l = t >> 6, i = t & 63;
        tym_s[t] = tym[((size_t)b * 16 + l) * SEQ + m0 + i];
        tyn_s[t] = tyn[((size_t)b * 16 + l) * SEQ + n0 + i];
    }
    if (tid < 64)       mrow_s[tid] = (float)amask[b * SEQ + m0 + tid];
    else if (tid < 128) mcol_s[tid - 64] = (float)amask[b * SEQ + n0 + (tid - 64)];
    __syncthreads();

    const int wave = tid >> 6;
    const int lane = tid & 63;
    const int quad = lane >> 4;
    const int nl   = lane & 15;

    short8 a0 = *(const short8*)(sA + (wave * 16 + nl) * 72 + quad * 8);
    short8 a1 = *(const short8*)(sA + (wave * 16 + nl) * 72 + 32 + quad * 8);

    floatx4 acc[4];
#pragma unroll
    for (int t = 0; t < 4; t++) acc[t] = (floatx4)(0.0f);
#pragma unroll
    for (int t = 0; t < 4; t++) {
        short8 bf0 = *(const short8*)(sB + (t * 16 + nl) * 72 + quad * 8);
        short8 bf1 = *(const short8*)(sB + (t * 16 + nl) * 72 + 32 + quad * 8);
        acc[t] = __builtin_amdgcn_mfma_f32_16x16x32_bf16(a0, bf0, acc[t], 0, 0, 0);
        acc[t] = __builtin_amdgcn_mfma_f32_16x16x32_bf16(a1, bf1, acc[t], 0, 0, 0);
    }

    float mr[4], radd[4];
#pragma unroll
    for (int r = 0; r < 4; r++) {
        mr[r]   = mrow_s[wave * 16 + quad * 4 + r];
        radd[r] = -NEGF * (1.0f - mr[r]);
    }
    float mc[4], cadd[4];
#pragma unroll
    for (int t = 0; t < 4; t++) {
        mc[t]   = mcol_s[t * 16 + nl];
        cadd[t] = -NEGF * (1.0f - mc[t]);
    }
    const bool lower = (m0 > n0);
    const bool diag  = (m0 == n0);
    const int  lm    = wave * 16 + quad * 4;

    for (int l = 0; l < 16; l++) {
        float tmv[4];
#pragma unroll
        for (int r = 0; r < 4; r++) tmv[r] = tym_s[l * 64 + lm + r];
        float* ob = out + ((size_t)(b * 16 + l) * SEQ + m0 + lm) * SEQ + n0;
#pragma unroll
        for (int t = 0; t < 4; t++) {
            float tnv = tyn_s[l * 64 + t * 16 + nl];
#pragma unroll
            for (int r = 0; r < 4; r++) {
                float v = acc[t][r] + tnv + tmv[r];
                v = v * mr[r] + radd[r];
                v = v * mc[t] + cadd[t];
                if (lower) v -= NEGF;
                else if (diag && (lm + r > t * 16 + nl)) v -= NEGF;
                __builtin_nontemporal_store(v, ob + (size_t)r * SEQ + t * 16 + nl);
            }
        }
    }
}

// ---------------------------------------------------------------------------
extern "C" void kernel_launch(void* const* d_in, const int* in_sizes, int n_in,
                              void* d_out, int out_size, void* d_ws, size_t ws_size,
                              hipStream_t stream) {
    const float* x     = (const float*)d_in[0];
    const float* W1    = (const float*)d_in[1];
    const float* b1    = (const float*)d_in[2];
    const float* W2    = (const float*)d_in[3];
    const float* b2    = (const float*)d_in[4];
    const int*   amask = (const int*)d_in[5];
    float* out = (float*)d_out;

    char* base = (char*)d_ws;
    unsigned short* startbf = (unsigned short*)base;                 // 4096*64*2 B
    unsigned short* endbf   = (unsigned short*)(base + 524288);
    float*          tyn     = (float*)(base + 2 * 524288);           // 8*16*512*4 B
    float*          tym     = (float*)(base + 2 * 524288 + 262144);

    hipLaunchKernelGGL(gemm_rope_fused_k, dim3(128), dim3(256), 0, stream,
                       x, W1, b1, W2, b2, startbf, endbf, tyn, tym);
    hipLaunchKernelGGL(entity_k, dim3(8, 8, 8), dim3(256), 0, stream,
                       startbf, endbf, tyn, tym, amask, out);
}

// Round 4
// 177.405 us; speedup vs baseline: 1.2343x; 1.2343x over previous
//
#include <hip/hip_runtime.h>

#define NEGF 1.0e12f

constexpr int Hdim = 768;
constexpr int NC   = 160;   // 128 (W1) + 32 (W2) output columns
constexpr int ROWS = 4096;  // B*S
constexpr int SEQ  = 512;
constexpr int KSPLIT = 4;   // K chunks of 192

typedef __attribute__((ext_vector_type(8))) short  short8;   // 8 bf16
typedef __attribute__((ext_vector_type(4))) float  floatx4;

__device__ inline unsigned short f2bf(float f) {
    union { float f; unsigned u; } v; v.f = f;
    return (unsigned short)((v.u + 0x8000u) >> 16);
}

// ---------------------------------------------------------------------------
// Kernel W-prep: Wt[c][k] = bf16([W1|W2][k][c]), c in [0,160), k in [0,768).
// 12 blocks x 256 threads; LDS-tiled transpose, coalesced both directions.
// ---------------------------------------------------------------------------
__global__ __launch_bounds__(256) void wprep_k(
    const float* __restrict__ W1, const float* __restrict__ W2,
    unsigned short* __restrict__ Wt)
{
    __shared__ __align__(16) unsigned short tile[160][72];  // [c][klocal]
    const int tid = threadIdx.x;
    const int k0  = blockIdx.x * 64;

    for (int t = tid; t < 64 * 32; t += 256) {   // W1: 64k x 128c, float4 tasks
        int k  = t >> 5;
        int c4 = (t & 31) * 4;
        float4 v = *(const float4*)(W1 + (size_t)(k0 + k) * 128 + c4);
        tile[c4 + 0][k] = f2bf(v.x); tile[c4 + 1][k] = f2bf(v.y);
        tile[c4 + 2][k] = f2bf(v.z); tile[c4 + 3][k] = f2bf(v.w);
    }
    for (int t = tid; t < 64 * 8; t += 256) {    // W2: 64k x 32c
        int k  = t >> 3;
        int c4 = (t & 7) * 4;
        float4 v = *(const float4*)(W2 + (size_t)(k0 + k) * 32 + c4);
        tile[128 + c4 + 0][k] = f2bf(v.x); tile[128 + c4 + 1][k] = f2bf(v.y);
        tile[128 + c4 + 2][k] = f2bf(v.z); tile[128 + c4 + 3][k] = f2bf(v.w);
    }
    __syncthreads();
    for (int t = tid; t < 160 * 8; t += 256) {   // store: short8 per task
        int c  = t >> 3;
        int kq = (t & 7) * 8;
        short8 v = *(const short8*)(&tile[c][kq]);
        *(short8*)(Wt + (size_t)c * 768 + k0 + kq) = v;
    }
}

// ---------------------------------------------------------------------------
// Kernel A: partial[kc] = x @ Wt^T over K-chunk kc, bf16 MFMA 16x16x32.
// Grid (64 row-blocks, 4 k-chunks) x 256 threads (4 waves).
// Block: 64 rows x 160 cols; wave w owns rows w*16..w*16+15, all 160 cols.
// ---------------------------------------------------------------------------
__global__ __launch_bounds__(256) void gemm_mfma_k(
    const float* __restrict__ x, const unsigned short* __restrict__ Wt,
    float* __restrict__ partial)
{
    __shared__ __align__(16) unsigned short xs[64 * 40];
    __shared__ __align__(16) unsigned short ws[NC * 40];

    const int tid  = threadIdx.x;
    const int wave = tid >> 6;
    const int lane = tid & 63;
    const int quad = lane >> 4;
    const int nl   = lane & 15;
    const int r0   = blockIdx.x * 64;
    const int k0   = blockIdx.y * 192;

    floatx4 acc[10];
#pragma unroll
    for (int t = 0; t < 10; t++) acc[t] = (floatx4)(0.0f);

    for (int kt = 0; kt < 192; kt += 32) {
        const int kb = k0 + kt;
        // stage x: 64 rows x 32 k -> bf16
        {
            const int row = tid >> 2;
            const int kq  = (tid & 3) * 8;
            const float* xp = x + (size_t)(r0 + row) * Hdim + kb + kq;
            float4 v0 = *(const float4*)xp;
            float4 v1 = *(const float4*)(xp + 4);
            short8 sv;
            sv[0] = (short)f2bf(v0.x); sv[1] = (short)f2bf(v0.y);
            sv[2] = (short)f2bf(v0.z); sv[3] = (short)f2bf(v0.w);
            sv[4] = (short)f2bf(v1.x); sv[5] = (short)f2bf(v1.y);
            sv[6] = (short)f2bf(v1.z); sv[7] = (short)f2bf(v1.w);
            *(short8*)(xs + row * 40 + kq) = sv;
        }
        // stage Wt tile: 160 c x 32 k bf16 = 640 short8 tasks
#pragma unroll
        for (int g = 0; g < 3; g++) {
            int task = g * 256 + tid;
            if (task < 640) {
                int c  = task >> 2;
                int kq = (task & 3) * 8;
                *(short8*)(ws + c * 40 + kq) =
                    *(const short8*)(Wt + (size_t)c * 768 + kb + kq);
            }
        }
        __syncthreads();

        short8 af = *(const short8*)(xs + (wave * 16 + nl) * 40 + quad * 8);
#pragma unroll
        for (int t = 0; t < 10; t++) {
            short8 bf = *(const short8*)(ws + (t * 16 + nl) * 40 + quad * 8);
            acc[t] = __builtin_amdgcn_mfma_f32_16x16x32_bf16(af, bf, acc[t], 0, 0, 0);
        }
        __syncthreads();
    }

    float* pout = partial + (size_t)blockIdx.y * ROWS * NC;
#pragma unroll
    for (int t = 0; t < 10; t++) {
#pragma unroll
        for (int r = 0; r < 4; r++) {
            pout[(size_t)(r0 + wave * 16 + quad * 4 + r) * NC + t * 16 + nl] = acc[t][r];
        }
    }
}

// ---------------------------------------------------------------------------
// Kernel B: combine 4 K-partials + bias, RoPE, emit bf16 start/end
// (start pre-scaled by 1/8) + fp32 typing planes.
// ---------------------------------------------------------------------------
__global__ __launch_bounds__(256) void combine_rope_k(
    const float* __restrict__ partial, const float* __restrict__ b1,
    const float* __restrict__ b2, unsigned short* __restrict__ startbf,
    unsigned short* __restrict__ endbf, float* __restrict__ tyn,
    float* __restrict__ tym)
{
    const int tid = threadIdx.x;
    const int row = blockIdx.x * 4 + (tid >> 6);
    const int u   = tid & 63;
    const int b   = row >> 9;
    const int s   = row & 511;
    const float* p0 = partial + (size_t)row * NC;
    const size_t cstride = (size_t)ROWS * NC;

    if (u < 32) {
        const int i = u;
        float4 a0 = *(const float4*)(p0 + 4 * i);
        float4 a1 = *(const float4*)(p0 + cstride + 4 * i);
        float4 a2 = *(const float4*)(p0 + 2 * cstride + 4 * i);
        float4 a3 = *(const float4*)(p0 + 3 * cstride + 4 * i);
        float t0 = a0.x + a1.x + a2.x + a3.x + b1[4 * i + 0];
        float t1 = a0.y + a1.y + a2.y + a3.y + b1[4 * i + 1];
        float t2 = a0.z + a1.z + a2.z + a3.z + b1[4 * i + 2];
        float t3 = a0.w + a1.w + a2.w + a3.w + b1[4 * i + 3];
        float freq = __powf(10000.0f, -(float)i * (1.0f / 32.0f));
        float ang  = (float)s * freq;
        float sn, cs;
        __sincosf(ang, &sn, &cs);
        float so0 = (t0 * cs - t2 * sn) * 0.125f;   // fold 1/sqrt(64)
        float so1 = (t2 * cs + t0 * sn) * 0.125f;
        float eo0 = t1 * cs - t3 * sn;
        float eo1 = t3 * cs + t1 * sn;
        ushort2 sp; sp.x = f2bf(so0); sp.y = f2bf(so1);
        ushort2 ep; ep.x = f2bf(eo0); ep.y = f2bf(eo1);
        *(ushort2*)(startbf + (size_t)row * 64 + 2 * i) = sp;
        *(ushort2*)(endbf   + (size_t)row * 64 + 2 * i) = ep;
    } else {
        const int j = u - 32;
        float t = p0[128 + j] + p0[cstride + 128 + j] + p0[2 * cstride + 128 + j]
                + p0[3 * cstride + 128 + j] + b2[j];
        float v = t * 0.5f;
        const int l = j >> 1;
        if ((j & 1) == 0) tyn[((size_t)b * 16 + l) * SEQ + s] = v;
        else              tym[((size_t)b * 16 + l) * SEQ + s] = v;
    }
}

// ---------------------------------------------------------------------------
// Kernel C: span = start.end^T via bf16 MFMA + 16-plane epilogue from D regs.
// Grid (8 n-tiles, 8 m-tiles, 8 batches) x 256 threads; 64x64 (m,n) tile.
// ---------------------------------------------------------------------------
__global__ __launch_bounds__(256) void entity_k(
    const unsigned short* __restrict__ startbf, const unsigned short* __restrict__ endbf,
    const float* __restrict__ tyn, const float* __restrict__ tym,
    const int* __restrict__ amask, float* __restrict__ out)
{
    __shared__ __align__(16) unsigned short sA[64 * 72];
    __shared__ __align__(16) unsigned short sB[64 * 72];
    __shared__ float tyn_s[16 * 64];
    __shared__ float tym_s[16 * 64];
    __shared__ float mrow_s[64];
    __shared__ float mcol_s[64];

    const int tid = threadIdx.x;
    const int b   = blockIdx.z;
    const int m0  = blockIdx.y * 64;
    const int n0  = blockIdx.x * 64;

    for (int t = tid; t < 512; t += 256) {
        int row = t >> 3;
        int kq  = (t & 7) * 8;
        *(short8*)(sA + row * 72 + kq) =
            *(const short8*)(startbf + (size_t)(b * SEQ + m0 + row) * 64 + kq);
        *(short8*)(sB + row * 72 + kq) =
            *(const short8*)(endbf + (size_t)(b * SEQ + n0 + row) * 64 + kq);
    }
    for (int t = tid; t < 16 * 64; t += 256) {
        int l = t >> 6, i = t & 63;
        tym_s[t] = tym[((size_t)b * 16 + l) * SEQ + m0 + i];
        tyn_s[t] = tyn[((size_t)b * 16 + l) * SEQ + n0 + i];
    }
    if (tid < 64)       mrow_s[tid] = (float)amask[b * SEQ + m0 + tid];
    else if (tid < 128) mcol_s[tid - 64] = (float)amask[b * SEQ + n0 + (tid - 64)];
    __syncthreads();

    const int wave = tid >> 6;
    const int lane = tid & 63;
    const int quad = lane >> 4;
    const int nl   = lane & 15;

    short8 a0 = *(const short8*)(sA + (wave * 16 + nl) * 72 + quad * 8);
    short8 a1 = *(const short8*)(sA + (wave * 16 + nl) * 72 + 32 + quad * 8);

    floatx4 acc[4];
#pragma unroll
    for (int t = 0; t < 4; t++) acc[t] = (floatx4)(0.0f);
#pragma unroll
    for (int t = 0; t < 4; t++) {
        short8 bf0 = *(const short8*)(sB + (t * 16 + nl) * 72 + quad * 8);
        short8 bf1 = *(const short8*)(sB + (t * 16 + nl) * 72 + 32 + quad * 8);
        acc[t] = __builtin_amdgcn_mfma_f32_16x16x32_bf16(a0, bf0, acc[t], 0, 0, 0);
        acc[t] = __builtin_amdgcn_mfma_f32_16x16x32_bf16(a1, bf1, acc[t], 0, 0, 0);
    }

    float mr[4], radd[4];
#pragma unroll
    for (int r = 0; r < 4; r++) {
        mr[r]   = mrow_s[wave * 16 + quad * 4 + r];
        radd[r] = -NEGF * (1.0f - mr[r]);
    }
    float mc[4], cadd[4];
#pragma unroll
    for (int t = 0; t < 4; t++) {
        mc[t]   = mcol_s[t * 16 + nl];
        cadd[t] = -NEGF * (1.0f - mc[t]);
    }
    const bool lower = (m0 > n0);
    const bool diag  = (m0 == n0);
    const int  lm    = wave * 16 + quad * 4;

    for (int l = 0; l < 16; l++) {
        float tmv[4];
#pragma unroll
        for (int r = 0; r < 4; r++) tmv[r] = tym_s[l * 64 + lm + r];
        float* ob = out + ((size_t)(b * 16 + l) * SEQ + m0 + lm) * SEQ + n0;
#pragma unroll
        for (int t = 0; t < 4; t++) {
            float tnv = tyn_s[l * 64 + t * 16 + nl];
#pragma unroll
            for (int r = 0; r < 4; r++) {
                float v = acc[t][r] + tnv + tmv[r];
                v = v * mr[r] + radd[r];
                v = v * mc[t] + cadd[t];
                if (lower) v -= NEGF;
                else if (diag && (lm + r > t * 16 + nl)) v -= NEGF;
                ob[(size_t)r * SEQ + t * 16 + nl] = v;
            }
        }
    }
}

// ---------------------------------------------------------------------------
extern "C" void kernel_launch(void* const* d_in, const int* in_sizes, int n_in,
                              void* d_out, int out_size, void* d_ws, size_t ws_size,
                              hipStream_t stream) {
    const float* x     = (const float*)d_in[0];
    const float* W1    = (const float*)d_in[1];
    const float* b1    = (const float*)d_in[2];
    const float* W2    = (const float*)d_in[3];
    const float* b2    = (const float*)d_in[4];
    const int*   amask = (const int*)d_in[5];
    float* out = (float*)d_out;

    char* base = (char*)d_ws;
    unsigned short* Wt      = (unsigned short*)base;                  // 160*768*2 = 245,760 B
    float*          partial = (float*)(base + 262144);                // 4*4096*160*4 = 10,485,760 B
    unsigned short* startbf = (unsigned short*)(base + 262144 + 10485760);
    unsigned short* endbf   = (unsigned short*)(base + 262144 + 10485760 + 524288);
    float*          tyn     = (float*)(base + 262144 + 10485760 + 2 * 524288);
    float*          tym     = (float*)(base + 262144 + 10485760 + 2 * 524288 + 262144);

    hipLaunchKernelGGL(wprep_k, dim3(12), dim3(256), 0, stream, W1, W2, Wt);
    hipLaunchKernelGGL(gemm_mfma_k, dim3(64, KSPLIT), dim3(256), 0, stream,
                       x, Wt, partial);
    hipLaunchKernelGGL(combine_rope_k, dim3(ROWS / 4), dim3(256), 0, stream,
                       partial, b1, b2, startbf, endbf, tyn, tym);
    hipLaunchKernelGGL(entity_k, dim3(8, 8, 8), dim3(256), 0, stream,
                       startbf, endbf, tyn, tym, amask, out);
}

// Round 5
// 170.045 us; speedup vs baseline: 1.2877x; 1.0433x over previous
//
#include <hip/hip_runtime.h>

#define NEGF 1.0e12f

constexpr int Hdim = 768;
constexpr int NC   = 160;   // 128 (W1) + 32 (W2) output columns
constexpr int ROWS = 4096;  // B*S
constexpr int SEQ  = 512;

typedef __attribute__((ext_vector_type(8))) short  short8;   // 8 bf16
typedef __attribute__((ext_vector_type(4))) float  floatx4;

__device__ inline unsigned short f2bf(float f) {
    union { float f; unsigned u; } v; v.f = f;
    return (unsigned short)((v.u + 0x8000u) >> 16);
}

// ---------------------------------------------------------------------------
// Kernel W-prep: Wt[c][k] = bf16([W1|W2][k][c]), c in [0,160), k in [0,768).
// 12 blocks x 256 threads; LDS-tiled transpose. (verbatim from R4, proven)
// ---------------------------------------------------------------------------
__global__ __launch_bounds__(256) void wprep_k(
    const float* __restrict__ W1, const float* __restrict__ W2,
    unsigned short* __restrict__ Wt)
{
    __shared__ __align__(16) unsigned short tile[160][72];
    const int tid = threadIdx.x;
    const int k0  = blockIdx.x * 64;

    for (int t = tid; t < 64 * 32; t += 256) {
        int k  = t >> 5;
        int c4 = (t & 31) * 4;
        float4 v = *(const float4*)(W1 + (size_t)(k0 + k) * 128 + c4);
        tile[c4 + 0][k] = f2bf(v.x); tile[c4 + 1][k] = f2bf(v.y);
        tile[c4 + 2][k] = f2bf(v.z); tile[c4 + 3][k] = f2bf(v.w);
    }
    for (int t = tid; t < 64 * 8; t += 256) {
        int k  = t >> 3;
        int c4 = (t & 7) * 4;
        float4 v = *(const float4*)(W2 + (size_t)(k0 + k) * 32 + c4);
        tile[128 + c4 + 0][k] = f2bf(v.x); tile[128 + c4 + 1][k] = f2bf(v.y);
        tile[128 + c4 + 2][k] = f2bf(v.z); tile[128 + c4 + 3][k] = f2bf(v.w);
    }
    __syncthreads();
    for (int t = tid; t < 160 * 8; t += 256) {
        int c  = t >> 3;
        int kq = (t & 7) * 8;
        short8 v = *(const short8*)(&tile[c][kq]);
        *(short8*)(Wt + (size_t)c * 768 + k0 + kq) = v;
    }
}

// ---------------------------------------------------------------------------
// Kernel AB: in-block split-K GEMM (16 rows x 160 cols x K=768) + rope.
// Grid 256 x 512 threads (8 waves). Wave w: K-chunk [w*96, w*96+96), 3 iters.
// No staging LDS, no in-loop barriers: A/B fragments loaded straight from
// global (x once; Wt L2-resident). One barrier -> LDS reduce -> rope/typing.
// ---------------------------------------------------------------------------
__global__ __launch_bounds__(512) void gemm_rope_k(
    const float* __restrict__ x, const unsigned short* __restrict__ Wt,
    const float* __restrict__ b1, const float* __restrict__ b2,
    unsigned short* __restrict__ startbf, unsigned short* __restrict__ endbf,
    float* __restrict__ tyn, float* __restrict__ tym)
{
    __shared__ __align__(16) float ts[8 * 16 * 160];   // 80 KB

    const int tid  = threadIdx.x;
    const int wave = tid >> 6;        // 0..7: K-chunk
    const int lane = tid & 63;
    const int quad = lane >> 4;
    const int nl   = lane & 15;
    const int r0   = blockIdx.x * 16;
    const int kbase = wave * 96;

    floatx4 acc[10];
#pragma unroll
    for (int t = 0; t < 10; t++) acc[t] = (floatx4)(0.0f);

#pragma unroll
    for (int it = 0; it < 3; it++) {
        const int kw = kbase + it * 32;
        // A fragment: x[r0+nl][kw + quad*8 .. +8] -> bf16
        const float* xp = x + (size_t)(r0 + nl) * Hdim + kw + quad * 8;
        float4 xa = *(const float4*)xp;
        float4 xb = *(const float4*)(xp + 4);
        // B fragments: Wt[t*16+nl][kw + quad*8 .. +8], already bf16
        short8 wr[10];
#pragma unroll
        for (int t = 0; t < 10; t++)
            wr[t] = *(const short8*)(Wt + (size_t)(t * 16 + nl) * Hdim + kw + quad * 8);

        short8 af;
        af[0] = (short)f2bf(xa.x); af[1] = (short)f2bf(xa.y);
        af[2] = (short)f2bf(xa.z); af[3] = (short)f2bf(xa.w);
        af[4] = (short)f2bf(xb.x); af[5] = (short)f2bf(xb.y);
        af[6] = (short)f2bf(xb.z); af[7] = (short)f2bf(xb.w);
#pragma unroll
        for (int t = 0; t < 10; t++)
            acc[t] = __builtin_amdgcn_mfma_f32_16x16x32_bf16(af, wr[t], acc[t], 0, 0, 0);
    }

    // partial -> LDS: D elem (t,r) at m-row quad*4+r, col t*16+nl
#pragma unroll
    for (int t = 0; t < 10; t++) {
#pragma unroll
        for (int r = 0; r < 4; r++) {
            ts[(wave * 16 + quad * 4 + r) * 160 + t * 16 + nl] = acc[t][r];
        }
    }
    __syncthreads();

    // epilogue: 16 rows x 64 units = 1024 units; 2 per thread
#pragma unroll
    for (int p = 0; p < 2; p++) {
        const int unit = tid + p * 512;
        const int lrow = unit >> 6;
        const int u    = unit & 63;
        const int grow = r0 + lrow;
        const int b    = grow >> 9;
        const int s    = grow & 511;
        if (u < 32) {
            const int i = u;
            float t0 = 0.0f, t1 = 0.0f, t2 = 0.0f, t3 = 0.0f;
#pragma unroll
            for (int w = 0; w < 8; w++) {
                float4 v = *(const float4*)(ts + (w * 16 + lrow) * 160 + 4 * i);
                t0 += v.x; t1 += v.y; t2 += v.z; t3 += v.w;
            }
            float4 bv = *(const float4*)(b1 + 4 * i);
            t0 += bv.x; t1 += bv.y; t2 += bv.z; t3 += bv.w;
            float freq = __powf(10000.0f, -(float)i * (1.0f / 32.0f));
            float ang  = (float)s * freq;
            float sn, cs;
            __sincosf(ang, &sn, &cs);
            float so0 = (t0 * cs - t2 * sn) * 0.125f;   // fold 1/sqrt(64)
            float so1 = (t2 * cs + t0 * sn) * 0.125f;
            float eo0 = t1 * cs - t3 * sn;
            float eo1 = t3 * cs + t1 * sn;
            ushort2 sp; sp.x = f2bf(so0); sp.y = f2bf(so1);
            ushort2 ep; ep.x = f2bf(eo0); ep.y = f2bf(eo1);
            *(ushort2*)(startbf + (size_t)grow * 64 + 2 * i) = sp;
            *(ushort2*)(endbf   + (size_t)grow * 64 + 2 * i) = ep;
        } else {
            const int j = u - 32;
            float t = 0.0f;
#pragma unroll
            for (int w = 0; w < 8; w++) t += ts[(w * 16 + lrow) * 160 + 128 + j];
            float v = (t + b2[j]) * 0.5f;
            const int l = j >> 1;
            if ((j & 1) == 0) tyn[((size_t)b * 16 + l) * SEQ + s] = v;
            else              tym[((size_t)b * 16 + l) * SEQ + s] = v;
        }
    }
}

// ---------------------------------------------------------------------------
// Kernel C: span = start.end^T via bf16 MFMA + 16-plane epilogue from D regs.
// Grid (8 n-tiles, 8 m-tiles, 8 batches) x 256 threads; 64x64 (m,n) tile.
// No LDS, no barriers: fragments + typing read straight from L2-resident ws.
// ---------------------------------------------------------------------------
__global__ __launch_bounds__(256) void entity_k(
    const unsigned short* __restrict__ startbf, const unsigned short* __restrict__ endbf,
    const float* __restrict__ tyn, const float* __restrict__ tym,
    const int* __restrict__ amask, float* __restrict__ out)
{
    const int tid = threadIdx.x;
    const int b   = blockIdx.z;
    const int m0  = blockIdx.y * 64;
    const int n0  = blockIdx.x * 64;

    const int wave = tid >> 6;
    const int lane = tid & 63;
    const int quad = lane >> 4;
    const int nl   = lane & 15;
    const int lm   = wave * 16 + quad * 4;   // local m-row of reg r=0

    // A fragments: start rows m0+wave*16+nl, k = quad*8..+8 and +32
    const unsigned short* arow = startbf + (size_t)(b * SEQ + m0 + wave * 16 + nl) * 64 + quad * 8;
    short8 a0 = *(const short8*)arow;
    short8 a1 = *(const short8*)(arow + 32);

    floatx4 acc[4];
#pragma unroll
    for (int t = 0; t < 4; t++) acc[t] = (floatx4)(0.0f);
#pragma unroll
    for (int t = 0; t < 4; t++) {
        const unsigned short* brow = endbf + (size_t)(b * SEQ + n0 + t * 16 + nl) * 64 + quad * 8;
        short8 bf0 = *(const short8*)brow;
        short8 bf1 = *(const short8*)(brow + 32);
        acc[t] = __builtin_amdgcn_mfma_f32_16x16x32_bf16(a0, bf0, acc[t], 0, 0, 0);
        acc[t] = __builtin_amdgcn_mfma_f32_16x16x32_bf16(a1, bf1, acc[t], 0, 0, 0);
    }

    // masks straight from global (tiny, L2)
    float mr[4], radd[4];
    {
        int4 mi = *(const int4*)(amask + b * SEQ + m0 + lm);
        mr[0] = (float)mi.x; mr[1] = (float)mi.y; mr[2] = (float)mi.z; mr[3] = (float)mi.w;
#pragma unroll
        for (int r = 0; r < 4; r++) radd[r] = -NEGF * (1.0f - mr[r]);
    }
    float mc[4], cadd[4];
#pragma unroll
    for (int t = 0; t < 4; t++) {
        mc[t]   = (float)amask[b * SEQ + n0 + t * 16 + nl];
        cadd[t] = -NEGF * (1.0f - mc[t]);
    }
    const bool lower = (m0 > n0);
    const bool diag  = (m0 == n0);

    for (int l = 0; l < 16; l++) {
        float4 tmv = *(const float4*)(tym + ((size_t)b * 16 + l) * SEQ + m0 + lm);
        float tnv[4];
#pragma unroll
        for (int t = 0; t < 4; t++)
            tnv[t] = tyn[((size_t)b * 16 + l) * SEQ + n0 + t * 16 + nl];
        float* ob = out + ((size_t)(b * 16 + l) * SEQ + m0 + lm) * SEQ + n0;
#pragma unroll
        for (int t = 0; t < 4; t++) {
#pragma unroll
            for (int r = 0; r < 4; r++) {
                float tm = (r == 0) ? tmv.x : (r == 1) ? tmv.y : (r == 2) ? tmv.z : tmv.w;
                float v = acc[t][r] + tnv[t] + tm;
                v = v * ((r == 0) ? mr[0] : (r == 1) ? mr[1] : (r == 2) ? mr[2] : mr[3])
                      + ((r == 0) ? radd[0] : (r == 1) ? radd[1] : (r == 2) ? radd[2] : radd[3]);
                v = v * mc[t] + cadd[t];
                if (lower) v -= NEGF;
                else if (diag && (lm + r > t * 16 + nl)) v -= NEGF;
                ob[(size_t)r * SEQ + t * 16 + nl] = v;
            }
        }
    }
}

// ---------------------------------------------------------------------------
extern "C" void kernel_launch(void* const* d_in, const int* in_sizes, int n_in,
                              void* d_out, int out_size, void* d_ws, size_t ws_size,
                              hipStream_t stream) {
    const float* x     = (const float*)d_in[0];
    const float* W1    = (const float*)d_in[1];
    const float* b1    = (const float*)d_in[2];
    const float* W2    = (const float*)d_in[3];
    const float* b2    = (const float*)d_in[4];
    const int*   amask = (const int*)d_in[5];
    float* out = (float*)d_out;

    char* base = (char*)d_ws;
    unsigned short* Wt      = (unsigned short*)base;                       // 245,760 B
    unsigned short* startbf = (unsigned short*)(base + 262144);            // 524,288 B
    unsigned short* endbf   = (unsigned short*)(base + 262144 + 524288);   // 524,288 B
    float*          tyn     = (float*)(base + 262144 + 2 * 524288);        // 262,144 B
    float*          tym     = (float*)(base + 262144 + 2 * 524288 + 262144);

    hipLaunchKernelGGL(wprep_k, dim3(12), dim3(256), 0, stream, W1, W2, Wt);
    hipLaunchKernelGGL(gemm_rope_k, dim3(256), dim3(512), 0, stream,
                       x, Wt, b1, b2, startbf, endbf, tyn, tym);
    hipLaunchKernelGGL(entity_k, dim3(8, 8, 8), dim3(256), 0, stream,
                       startbf, endbf, tyn, tym, amask, out);
}